// Round 7
// baseline (377.060 us; speedup 1.0000x reference)
//
#include <hip/hip_runtime.h>

#define EPS 1e-5f
constexpr int HD = 128;   // node feature / hidden dim
constexpr int FCD = 64;   // fc hidden dim

typedef __attribute__((ext_vector_type(8))) short short8;
typedef __attribute__((ext_vector_type(4))) float floatx4;

// ---------- bf16 helpers ----------
__device__ inline ushort f2bf(float f){
  union{float f; unsigned u;} v; v.f = f;
  unsigned r = v.u + 0x7FFFu + ((v.u >> 16) & 1u);
  return (ushort)(r >> 16);
}
__device__ inline float bflo(unsigned u){ union{unsigned i; float f;} v; v.i = u << 16;        return v.f; }
__device__ inline float bfhi(unsigned u){ union{unsigned i; float f;} v; v.i = u & 0xFFFF0000u; return v.f; }
__device__ inline float bf2f(ushort u){ union{unsigned i; float f;} v; v.i = ((unsigned)u) << 16; return v.f; }

// ================= preprocessing =================
// k_pre: fused [bucket histogram | W fragment pack | pooled zeroing]
__global__ __launch_bounds__(256) void k_pre(const int* __restrict__ dst,
                                             int* __restrict__ bucketHist, int E, int nEB,
                                             const float* __restrict__ W1,
                                             const float* __restrict__ W2,
                                             const float* __restrict__ W3,
                                             ushort* __restrict__ Wf,
                                             float* __restrict__ pooled, int poolSz){
  __shared__ int h[256];
  int bid = blockIdx.x, t = threadIdx.x;
  if (bid < nEB){
    h[t] = 0;
    __syncthreads();
    int base = bid*4096;
    #pragma unroll
    for (int k = 0; k < 16; ++k){
      int e = base + k*256 + t;
      if (e < E) atomicAdd(&h[dst[e] >> 8], 1);
    }
    __syncthreads();
    if (h[t]) atomicAdd(&bucketHist[t], h[t]);
  } else if (bid < nEB + 192){
    int j = bid - nEB;
    int l = j >> 6;
    int idx = (j & 63)*256 + t;             // 0..16383
    const float* W = (l == 0) ? W1 : (l == 1) ? W2 : W3;
    float w = W[idx];
    int k = idx >> 7, n = idx & 127;
    int kb = k >> 5, q4 = (k >> 3) & 3, jj = k & 7;
    int nt = n >> 4, col = n & 15;
    Wf[(size_t)l*16384 + (((size_t)(kb*8 + nt)*64 + q4*16 + col)*8 + jj)] = f2bf(w);
  } else {
    int j = bid - nEB - 192;
    int base = (j*256 + t)*4;
    #pragma unroll
    for (int k = 0; k < 4; ++k){
      int o = base + k;
      if (o < poolSz) pooled[o] = 0.f;
    }
  }
}

// 1 block: exclusive scan of 256 bucket counts -> base & cursor
__global__ __launch_bounds__(256) void k_bscan(const int* __restrict__ bucketHist,
                                               int* __restrict__ bucketBase,
                                               int* __restrict__ bucketCursor){
  __shared__ int wt[4];
  int t = threadIdx.x, lane = t & 63, w = t >> 6;
  int v = bucketHist[t];
  int incl = v;
  #pragma unroll
  for (int o = 1; o < 64; o <<= 1){
    int x = __shfl_up(incl, o, 64);
    if (lane >= o) incl += x;
  }
  if (lane == 63) wt[w] = incl;
  __syncthreads();
  int woff = 0;
  for (int i = 0; i < w; ++i) woff += wt[i];
  int ex = woff + incl - v;
  bucketBase[t] = ex;
  bucketCursor[t] = ex;
}

// LDS-staged bucket scatter; edge packed into one int: src | (dst&255)<<16
__global__ __launch_bounds__(256) void k_bucket(const int* __restrict__ src,
                                                const int* __restrict__ dst,
                                                int* __restrict__ bucketCursor,
                                                int* __restrict__ tmp, int E){
  __shared__ int h[256], ls[256], cur[256], gb[256];
  __shared__ int wt[4];
  __shared__ int staged[4096];
  __shared__ unsigned char bos[4096];
  int t = threadIdx.x, lane = t & 63, w = t >> 6;
  int base = blockIdx.x*4096;
  int ed[16]; int bk[16];
  h[t] = 0;
  __syncthreads();
  #pragma unroll
  for (int k = 0; k < 16; ++k){
    int e = base + k*256 + t;
    if (e < E){
      int s = src[e], d = dst[e];
      ed[k] = s | ((d & 255) << 16);
      bk[k] = d >> 8;
      atomicAdd(&h[bk[k]], 1);
    } else bk[k] = -1;
  }
  __syncthreads();
  int v = h[t];
  int incl = v;
  #pragma unroll
  for (int o = 1; o < 64; o <<= 1){
    int x = __shfl_up(incl, o, 64);
    if (lane >= o) incl += x;
  }
  if (lane == 63) wt[w] = incl;
  __syncthreads();
  int woff = 0;
  for (int i = 0; i < w; ++i) woff += wt[i];
  ls[t] = woff + incl - v;
  cur[t] = ls[t];
  if (v > 0) gb[t] = atomicAdd(&bucketCursor[t], v);
  __syncthreads();
  #pragma unroll
  for (int k = 0; k < 16; ++k){
    if (bk[k] >= 0){
      int lp = atomicAdd(&cur[bk[k]], 1);
      staged[lp] = ed[k];
      bos[lp] = (unsigned char)bk[k];
    }
  }
  __syncthreads();
  int nvalid = min(4096, E - base);
  #pragma unroll
  for (int k = 0; k < 16; ++k){
    int i = k*256 + t;
    if (i < nvalid){
      int b = bos[i];
      tmp[gb[b] + (i - ls[b])] = staged[i];
    }
  }
}

// one block per bucket: group by exact dst, emit rowptr/dis/csrc
__global__ __launch_bounds__(256) void k_csr(const int* __restrict__ tmp,
                                             const int* __restrict__ bucketHist,
                                             const int* __restrict__ bucketBase,
                                             int* __restrict__ rowptr,
                                             float* __restrict__ dis,
                                             int* __restrict__ csrc, int N){
  __shared__ int h[256], ls[256], cur[256];
  __shared__ int wt[4];
  __shared__ int stagedSrc[6144];
  int b = blockIdx.x, t = threadIdx.x, lane = t & 63, w = t >> 6;
  int ebase = bucketBase[b];
  int cnt = bucketHist[b];
  int node0 = b << 8;
  h[t] = 0;
  __syncthreads();
  for (int i = t; i < cnt; i += 256)
    atomicAdd(&h[(tmp[ebase + i] >> 16) & 255], 1);
  __syncthreads();
  int v = h[t];
  int incl = v;
  #pragma unroll
  for (int o = 1; o < 64; o <<= 1){
    int x = __shfl_up(incl, o, 64);
    if (lane >= o) incl += x;
  }
  if (lane == 63) wt[w] = incl;
  __syncthreads();
  int woff = 0;
  for (int i = 0; i < w; ++i) woff += wt[i];
  int ex = woff + incl - v;
  ls[t] = ex; cur[t] = ex;
  int d = node0 + t;
  if (d < N){
    rowptr[d+1] = ebase + ex + v;
    dis[d] = rsqrtf((float)v + 1.0f);
  }
  if (b == 0 && t == 0) rowptr[0] = 0;
  __syncthreads();
  for (int i = t; i < cnt; i += 256){
    int e = tmp[ebase + i];
    int lp = atomicAdd(&cur[(e >> 16) & 255], 1);
    stagedSrc[lp] = e & 0xFFFF;
  }
  __syncthreads();
  for (int i = t; i < cnt; i += 256)
    csrc[ebase + i] = stagedSrc[i];
}

// ------------------- GEMM: bf16 MFMA, fused BN-affine+ReLU on A, dis-scale on out ----
// A (MODE 1) and O are PASS-MAJOR: [pass][node][32ch], pass = k-block / out-ch-block.
template<int MODE>
__global__ __launch_bounds__(256) void k_gemm(const void* __restrict__ Av,
                                              const ushort* __restrict__ Wf,
                                              const float* __restrict__ sums,
                                              const float* __restrict__ g,
                                              const float* __restrict__ be,
                                              const float* __restrict__ dis,
                                              ushort* __restrict__ O, int n, float invN){
  __shared__ float aL[HD], bL[HD];
  int tid = threadIdx.x;
  if (MODE){
    if (tid < HD){
      float m = sums[tid]*invN;
      float var = fmaxf(sums[HD+tid]*invN - m*m, 0.f);
      float Ac = g[tid]*rsqrtf(var + EPS);
      aL[tid] = Ac; bL[tid] = be[tid] - m*Ac;
    }
    __syncthreads();
  }
  int lane = tid & 63, wave = tid >> 6;
  int quad = lane >> 4, r16 = lane & 15;
  int row = blockIdx.x*64 + wave*16 + r16;
  int rowc = min(row, n-1);
  floatx4 acc[8] = {};
  #pragma unroll
  for (int kb = 0; kb < 4; ++kb){
    int k0 = kb*32 + quad*8;
    short8 af;
    if (MODE){
      // pass-major read: pass = kb
      const ushort* Ap = (const ushort*)Av + ((size_t)kb*n + rowc)*32 + quad*8;
      short8 raw = *(const short8*)Ap;
      #pragma unroll
      for (int jj = 0; jj < 8; ++jj){
        float f = bf2f((ushort)raw[jj]);
        f = fmaxf(f*aL[k0+jj] + bL[k0+jj], 0.f);
        af[jj] = (short)f2bf(f);
      }
    } else {
      const float* Arow = (const float*)Av + (size_t)rowc*HD;
      float4 x0 = *(const float4*)(Arow + k0);
      float4 x1 = *(const float4*)(Arow + k0 + 4);
      af[0] = (short)f2bf(x0.x); af[1] = (short)f2bf(x0.y);
      af[2] = (short)f2bf(x0.z); af[3] = (short)f2bf(x0.w);
      af[4] = (short)f2bf(x1.x); af[5] = (short)f2bf(x1.y);
      af[6] = (short)f2bf(x1.z); af[7] = (short)f2bf(x1.w);
    }
    const ushort* wp = Wf + ((size_t)(kb*8)*64 + lane)*8;
    #pragma unroll
    for (int nt = 0; nt < 8; ++nt){
      short8 bf = *(const short8*)(wp + (size_t)nt*64*8);
      acc[nt] = __builtin_amdgcn_mfma_f32_16x16x32_bf16(af, bf, acc[nt], 0, 0, 0);
    }
  }
  int rbase = blockIdx.x*64 + wave*16 + quad*4;
  float ds[4];
  #pragma unroll
  for (int r = 0; r < 4; ++r) ds[r] = dis[min(rbase + r, n-1)];
  #pragma unroll
  for (int nt = 0; nt < 8; ++nt){
    int p = nt >> 1, cp = (nt & 1)*16 + r16;   // pass, channel-in-pass
    #pragma unroll
    for (int r = 0; r < 4; ++r){
      int rr = rbase + r;
      if (rr < n) O[((size_t)p*n + rr)*32 + cp] = f2bf(acc[nt][r]*ds[r]);
    }
  }
}

// ------------------- edge aggregation, ONE COLUMN PASS (32 ch) + stats -------------------
// 4 lanes/node x 16B, 64 nodes/block. Working set per pass = N*64B = 3.2MB -> fits XCD L2.
__global__ __launch_bounds__(256) void k_gatherp(const ushort* __restrict__ hwAll,
                                                 const int* __restrict__ rowptr,
                                                 const int* __restrict__ csrc,
                                                 const float* __restrict__ dis,
                                                 ushort* __restrict__ aggAll,
                                                 float* __restrict__ scratch,
                                                 float* __restrict__ sums,
                                                 int N, int pass, int NBg){
  __shared__ float2 sm[4][32];
  if (pass == 0 && blockIdx.x == 0) sums[threadIdx.x] = 0.f;   // zero before k_reduce
  const ushort* hw = hwAll + (size_t)pass*N*32;
  ushort* agg = aggAll + (size_t)pass*N*32;
  int t = threadIdx.x;
  int nodein = t >> 2, cg = t & 3;
  int wave = t >> 6, lane = t & 63;
  int i = blockIdx.x*64 + nodein;
  bool valid = (i < N);
  int ic = valid ? i : N-1;
  uint4 q = *(const uint4*)(hw + (size_t)ic*32 + cg*8);
  float a[8];
  a[0] = bflo(q.x); a[1] = bfhi(q.x);
  a[2] = bflo(q.y); a[3] = bfhi(q.y);
  a[4] = bflo(q.z); a[5] = bfhi(q.z);
  a[6] = bflo(q.w); a[7] = bfhi(q.w);
  int e = rowptr[ic], e1 = rowptr[ic+1];
  #define ADD8(Q) \
    a[0] += bflo(Q.x); a[1] += bfhi(Q.x); \
    a[2] += bflo(Q.y); a[3] += bfhi(Q.y); \
    a[4] += bflo(Q.z); a[5] += bfhi(Q.z); \
    a[6] += bflo(Q.w); a[7] += bfhi(Q.w);
  while (e < e1 && (e & 3)){
    uint4 qq = *(const uint4*)(hw + (size_t)csrc[e]*32 + cg*8);
    ADD8(qq);
    e++;
  }
  int4 c0, c1;
  if (e + 8 <= e1){
    c0 = *(const int4*)&csrc[e];
    c1 = *(const int4*)&csrc[e+4];
  }
  while (e + 8 <= e1){
    int en = e + 8;
    int4 n0, n1;
    if (en + 8 <= e1){
      n0 = *(const int4*)&csrc[en];
      n1 = *(const int4*)&csrc[en+4];
    }
    uint4 q0 = *(const uint4*)(hw + (size_t)c0.x*32 + cg*8);
    uint4 q1 = *(const uint4*)(hw + (size_t)c0.y*32 + cg*8);
    uint4 q2 = *(const uint4*)(hw + (size_t)c0.z*32 + cg*8);
    uint4 q3 = *(const uint4*)(hw + (size_t)c0.w*32 + cg*8);
    uint4 q4 = *(const uint4*)(hw + (size_t)c1.x*32 + cg*8);
    uint4 q5 = *(const uint4*)(hw + (size_t)c1.y*32 + cg*8);
    uint4 q6 = *(const uint4*)(hw + (size_t)c1.z*32 + cg*8);
    uint4 q7 = *(const uint4*)(hw + (size_t)c1.w*32 + cg*8);
    ADD8(q0); ADD8(q1); ADD8(q2); ADD8(q3);
    ADD8(q4); ADD8(q5); ADD8(q6); ADD8(q7);
    c0 = n0; c1 = n1; e = en;
  }
  if (e + 4 <= e1){
    int4 tt = *(const int4*)&csrc[e];
    uint4 q0 = *(const uint4*)(hw + (size_t)tt.x*32 + cg*8);
    uint4 q1 = *(const uint4*)(hw + (size_t)tt.y*32 + cg*8);
    uint4 q2 = *(const uint4*)(hw + (size_t)tt.z*32 + cg*8);
    uint4 q3 = *(const uint4*)(hw + (size_t)tt.w*32 + cg*8);
    ADD8(q0); ADD8(q1); ADD8(q2); ADD8(q3);
    e += 4;
  }
  for (; e < e1; ++e){
    uint4 qq = *(const uint4*)(hw + (size_t)csrc[e]*32 + cg*8);
    ADD8(qq);
  }
  #undef ADD8
  float sc = dis[ic];
  #pragma unroll
  for (int k = 0; k < 8; ++k) a[k] *= sc;
  if (valid){
    uint4 o;
    o.x = (unsigned)f2bf(a[0]) | ((unsigned)f2bf(a[1]) << 16);
    o.y = (unsigned)f2bf(a[2]) | ((unsigned)f2bf(a[3]) << 16);
    o.z = (unsigned)f2bf(a[4]) | ((unsigned)f2bf(a[5]) << 16);
    o.w = (unsigned)f2bf(a[6]) | ((unsigned)f2bf(a[7]) << 16);
    *(uint4*)(agg + (size_t)i*32 + cg*8) = o;
  }
  // stats: reduce over 16 nodes in wave (xor 4/8/16/32), combine 4 waves in LDS
  float z = valid ? 1.f : 0.f;
  float rs[8], rq[8];
  #pragma unroll
  for (int k = 0; k < 8; ++k){
    float s = a[k]*z, qq = a[k]*a[k]*z;
    s  += __shfl_xor(s, 4);  s  += __shfl_xor(s, 8);  s  += __shfl_xor(s, 16);  s  += __shfl_xor(s, 32);
    qq += __shfl_xor(qq, 4); qq += __shfl_xor(qq, 8); qq += __shfl_xor(qq, 16); qq += __shfl_xor(qq, 32);
    rs[k] = s; rq[k] = qq;
  }
  if (lane < 4){
    #pragma unroll
    for (int k = 0; k < 8; ++k) sm[wave][lane*8 + k] = make_float2(rs[k], rq[k]);
  }
  __syncthreads();
  size_t base = ((size_t)pass*NBg + blockIdx.x)*64;
  if (t < 32)
    scratch[base + t] = sm[0][t].x + sm[1][t].x + sm[2][t].x + sm[3][t].x;
  else if (t < 64){
    int c = t - 32;
    scratch[base + t] = sm[0][c].y + sm[1][c].y + sm[2][c].y + sm[3][c].y;
  }
}

// second-stage reduction over all pass-blocks -> sums[0..127]=sum, [128..255]=sumsq
__global__ __launch_bounds__(256) void k_reduce(const float* __restrict__ scratch,
                                                float* __restrict__ sums, int NBg){
  int t = threadIdx.x;
  int isq = t >> 7;
  int c = t & 127;
  int p = c >> 5, cc = c & 31;
  float acc = 0.f;
  for (int b = blockIdx.x; b < NBg; b += gridDim.x)
    acc += scratch[((size_t)p*NBg + b)*64 + isq*32 + cc];
  atomicAdd(&sums[t], acc);
}

// ------------------- mean pool (fused layer-3 BN+ReLU, fused counts) -------------------
// AGG is pass-major.
__global__ __launch_bounds__(128) void k_pool(const ushort* __restrict__ h,
                                              const int* __restrict__ batch,
                                              const float* __restrict__ sums,
                                              const float* __restrict__ g,
                                              const float* __restrict__ be,
                                              float* __restrict__ pooled,
                                              float* __restrict__ cntf, int N, float invN){
  int c = threadIdx.x;
  float m = sums[c]*invN;
  float var = fmaxf(sums[HD+c]*invN - m*m, 0.f);
  float a = g[c]*rsqrtf(var + EPS);
  float b = be[c] - m*a;
  const ushort* hp = h + (size_t)(c >> 5)*N*32 + (c & 31);
  int start = blockIdx.x * 32;
  if (start >= N) return;
  int end = min(start + 32, N);
  int cur = batch[start];
  float acc = 0.f; int run = 0;
  for (int i = start; i < end; ++i){
    int bb = batch[i];
    if (bb != cur){
      atomicAdd(&pooled[(size_t)cur*HD + c], acc);
      if (c == 0) atomicAdd(&cntf[cur], (float)run);
      acc = 0.f; run = 0; cur = bb;
    }
    acc += fmaxf(bf2f(hp[(size_t)i*32])*a + b, 0.f);
    run++;
  }
  atomicAdd(&pooled[(size_t)cur*HD + c], acc);
  if (c == 0) atomicAdd(&cntf[cur], (float)run);
}

// ------------------- FC head -------------------

__global__ __launch_bounds__(64) void k_fc1(const float* __restrict__ pooled,
                                            const float* __restrict__ cntf,
                                            const float* __restrict__ W,
                                            const float* __restrict__ b,
                                            float* __restrict__ z,
                                            float* __restrict__ sums2, int G){
  int g = blockIdx.x, j = threadIdx.x;
  if (g == 0){ sums2[j] = 0.f; sums2[FCD + j] = 0.f; }
  float inv = 1.0f / fmaxf(cntf[g], 1.0f);
  float acc = 0.f;
  for (int k = 0; k < HD; ++k)
    acc += pooled[(size_t)g*HD + k] * W[k*FCD + j];
  z[(size_t)g*FCD + j] = acc * inv + b[j];
}

__global__ __launch_bounds__(64) void k_stats2(const float* __restrict__ z,
                                               float* __restrict__ sums2, int G){
  int c = threadIdx.x;
  float s = 0.f, q = 0.f;
  for (int i = blockIdx.x; i < G; i += gridDim.x){
    float v = z[(size_t)i*FCD + c]; s += v; q += v*v;
  }
  atomicAdd(&sums2[c], s);
  atomicAdd(&sums2[FCD + c], q);
}

__global__ __launch_bounds__(64) void k_final(const float* __restrict__ z,
                                              const float* __restrict__ sums2,
                                              const float* __restrict__ g,
                                              const float* __restrict__ be,
                                              const float* __restrict__ w2,
                                              const float* __restrict__ b2,
                                              float* __restrict__ out, int G, float invG){
  int gg = blockIdx.x, c = threadIdx.x;
  float m = sums2[c]*invG;
  float var = fmaxf(sums2[FCD+c]*invG - m*m, 0.f);
  float A = g[c]*rsqrtf(var + EPS);
  float B = be[c] - m*A;
  float v = fmaxf(z[(size_t)gg*FCD + c]*A + B, 0.f) * w2[c];
  #pragma unroll
  for (int o = 32; o > 0; o >>= 1) v += __shfl_down(v, o, 64);
  if (c == 0) out[gg] = v + b2[0];
}

// ------------------- launch -------------------

extern "C" void kernel_launch(void* const* d_in, const int* in_sizes, int n_in,
                              void* d_out, int out_size, void* d_ws, size_t ws_size,
                              hipStream_t stream){
  const float* x    = (const float*)d_in[0];
  const int*   ei   = (const int*)d_in[1];
  const int*   batch= (const int*)d_in[2];
  const float* W1 = (const float*)d_in[3];
  const float* g1 = (const float*)d_in[5];
  const float* be1= (const float*)d_in[6];
  const float* W2 = (const float*)d_in[7];
  const float* g2 = (const float*)d_in[9];
  const float* be2= (const float*)d_in[10];
  const float* W3 = (const float*)d_in[11];
  const float* g3 = (const float*)d_in[13];
  const float* be3= (const float*)d_in[14];
  const float* fcW1 = (const float*)d_in[15];
  const float* fcb1 = (const float*)d_in[16];
  const float* fcg1 = (const float*)d_in[17];
  const float* fcbe1= (const float*)d_in[18];
  const float* fcW2 = (const float*)d_in[19];
  const float* fcb2 = (const float*)d_in[20];
  float* out = (float*)d_out;

  const int N = in_sizes[0] / HD;      // 50000 (fits 16-bit pack: N < 65536)
  const int E = in_sizes[1] / 2;       // 800000
  const int G = out_size;              // 500

  const int* esrc = ei;
  const int* edst = ei + E;

  char* p = (char*)d_ws;
  auto alloc = [&](size_t bytes)->void*{
    void* r = (void*)p; p += (bytes + 255) & ~(size_t)255; return r;
  };
  int NBg = (N + 63)/64;               // 782 gather blocks per pass
  int nEB = (E + 4095)/4096;           // 196 edge blocks
  int NB  = (N + 255)/256;             // 196 node buckets (<=256 required)
  int poolSz = G*HD + G;
  int PZ = (poolSz + 1023)/1024;
  int*    bucketHist  = (int*) alloc(256*4);
  int*    bucketBase  = (int*) alloc(256*4);
  int*    bucketCursor= (int*) alloc(256*4);
  int*    tmp    = (int*)   alloc((size_t)E*4);
  int*    rowptr = (int*)   alloc((size_t)(N+1)*4);
  int*    csrc   = (int*)   alloc((size_t)E*4);
  float*  dis    = (float*) alloc((size_t)N*4);
  ushort* HWb    = (ushort*)alloc((size_t)N*HD*2);   // pass-major [4][N][32]
  ushort* AGG    = (ushort*)alloc((size_t)N*HD*2);   // pass-major [4][N][32]
  ushort* Wf     = (ushort*)alloc((size_t)3*HD*HD*2);
  float*  sums   = (float*) alloc(2*HD*4);
  float*  scratch= (float*) alloc((size_t)4*NBg*64*4);
  float*  pooled = (float*) alloc(((size_t)G*HD + G)*4);
  float*  cntf   = pooled + (size_t)G*HD;
  float*  zbuf   = (float*) alloc((size_t)G*FCD*4);
  float*  sums2  = (float*) alloc(2*FCD*4);

  float invN = 1.0f/(float)N, invG = 1.0f/(float)G;

  // CSR build (bucket sort) + fused W-pack + pooled zero
  hipMemsetAsync(bucketHist, 0, 256*4, stream);
  k_pre   <<<nEB + 192 + PZ, 256, 0, stream>>>(edst, bucketHist, E, nEB,
                                               W1, W2, W3, Wf, pooled, poolSz);
  k_bscan <<<1, 256, 0, stream>>>(bucketHist, bucketBase, bucketCursor);
  k_bucket<<<nEB, 256, 0, stream>>>(esrc, edst, bucketCursor, tmp, E);
  k_csr   <<<NB, 256, 0, stream>>>(tmp, bucketHist, bucketBase, rowptr, dis, csrc, N);

  int gemmBlocks = (N + 63)/64;

  // layer 1
  k_gemm<0> <<<gemmBlocks, 256, 0, stream>>>(x,   Wf,         nullptr, nullptr, nullptr, dis, HWb, N, invN);
  for (int pp = 0; pp < 4; ++pp)
    k_gatherp<<<NBg, 256, 0, stream>>>(HWb, rowptr, csrc, dis, AGG, scratch, sums, N, pp, NBg);
  k_reduce  <<<64, 256, 0, stream>>>(scratch, sums, NBg);
  // layer 2 (BN1+ReLU fused into A-load)
  k_gemm<1> <<<gemmBlocks, 256, 0, stream>>>(AGG, Wf + 16384, sums, g1, be1, dis, HWb, N, invN);
  for (int pp = 0; pp < 4; ++pp)
    k_gatherp<<<NBg, 256, 0, stream>>>(HWb, rowptr, csrc, dis, AGG, scratch, sums, N, pp, NBg);
  k_reduce  <<<64, 256, 0, stream>>>(scratch, sums, NBg);
  // layer 3 (BN2+ReLU fused into A-load)
  k_gemm<1> <<<gemmBlocks, 256, 0, stream>>>(AGG, Wf + 32768, sums, g2, be2, dis, HWb, N, invN);
  for (int pp = 0; pp < 4; ++pp)
    k_gatherp<<<NBg, 256, 0, stream>>>(HWb, rowptr, csrc, dis, AGG, scratch, sums, N, pp, NBg);
  k_reduce  <<<64, 256, 0, stream>>>(scratch, sums, NBg);

  // pool (BN3+ReLU fused) + head
  k_pool  <<<(N+31)/32, 128, 0, stream>>>(AGG, batch, sums, g3, be3, pooled, cntf, N, invN);
  k_fc1   <<<G, FCD, 0, stream>>>(pooled, cntf, fcW1, fcb1, zbuf, sums2, G);
  k_stats2<<<64, FCD, 0, stream>>>(zbuf, sums2, G);
  k_final <<<G, FCD, 0, stream>>>(zbuf, sums2, fcg1, fcbe1, fcW2, fcb2, out, G, invG);
}

// Round 8
// 366.319 us; speedup vs baseline: 1.0293x; 1.0293x over previous
//
#include <hip/hip_runtime.h>

#define EPS 1e-5f
constexpr int HD = 128;   // node feature / hidden dim
constexpr int FCD = 64;   // fc hidden dim

typedef __attribute__((ext_vector_type(8))) short short8;
typedef __attribute__((ext_vector_type(4))) float floatx4;

// ---------- bf16 helpers ----------
__device__ inline ushort f2bf(float f){
  union{float f; unsigned u;} v; v.f = f;
  unsigned r = v.u + 0x7FFFu + ((v.u >> 16) & 1u);
  return (ushort)(r >> 16);
}
__device__ inline float bflo(unsigned u){ union{unsigned i; float f;} v; v.i = u << 16;        return v.f; }
__device__ inline float bfhi(unsigned u){ union{unsigned i; float f;} v; v.i = u & 0xFFFF0000u; return v.f; }
__device__ inline float bf2f(ushort u){ union{unsigned i; float f;} v; v.i = ((unsigned)u) << 16; return v.f; }

// ================= preprocessing =================
// k_pre: fused [bucket histogram | W fragment pack | pooled+cntf zeroing]
__global__ __launch_bounds__(256) void k_pre(const int* __restrict__ dst,
                                             int* __restrict__ bucketHist, int E, int nEB,
                                             const float* __restrict__ W1,
                                             const float* __restrict__ W2,
                                             const float* __restrict__ W3,
                                             ushort* __restrict__ Wf,
                                             float* __restrict__ pooled, int poolSz){
  __shared__ int h[256];
  int bid = blockIdx.x, t = threadIdx.x;
  if (bid < nEB){
    h[t] = 0;
    __syncthreads();
    int base = bid*4096;
    #pragma unroll
    for (int k = 0; k < 16; ++k){
      int e = base + k*256 + t;
      if (e < E) atomicAdd(&h[dst[e] >> 8], 1);
    }
    __syncthreads();
    if (h[t]) atomicAdd(&bucketHist[t], h[t]);
  } else if (bid < nEB + 192){
    int j = bid - nEB;
    int l = j >> 6;
    int idx = (j & 63)*256 + t;             // 0..16383
    const float* W = (l == 0) ? W1 : (l == 1) ? W2 : W3;
    float w = W[idx];
    int k = idx >> 7, n = idx & 127;
    int kb = k >> 5, q4 = (k >> 3) & 3, jj = k & 7;
    int nt = n >> 4, col = n & 15;
    Wf[(size_t)l*16384 + (((size_t)(kb*8 + nt)*64 + q4*16 + col)*8 + jj)] = f2bf(w);
  } else {
    int j = bid - nEB - 192;
    int base = (j*256 + t)*4;
    #pragma unroll
    for (int k = 0; k < 4; ++k){
      int o = base + k;
      if (o < poolSz) pooled[o] = 0.f;
    }
  }
}

// 1 block: exclusive scan of 256 bucket counts -> base & cursor
__global__ __launch_bounds__(256) void k_bscan(const int* __restrict__ bucketHist,
                                               int* __restrict__ bucketBase,
                                               int* __restrict__ bucketCursor){
  __shared__ int wt[4];
  int t = threadIdx.x, lane = t & 63, w = t >> 6;
  int v = bucketHist[t];
  int incl = v;
  #pragma unroll
  for (int o = 1; o < 64; o <<= 1){
    int x = __shfl_up(incl, o, 64);
    if (lane >= o) incl += x;
  }
  if (lane == 63) wt[w] = incl;
  __syncthreads();
  int woff = 0;
  for (int i = 0; i < w; ++i) woff += wt[i];
  int ex = woff + incl - v;
  bucketBase[t] = ex;
  bucketCursor[t] = ex;
}

// LDS-staged bucket scatter; edge packed into one int: src | (dst&255)<<16
__global__ __launch_bounds__(256) void k_bucket(const int* __restrict__ src,
                                                const int* __restrict__ dst,
                                                int* __restrict__ bucketCursor,
                                                int* __restrict__ tmp, int E){
  __shared__ int h[256], ls[256], cur[256], gb[256];
  __shared__ int wt[4];
  __shared__ int staged[4096];
  __shared__ unsigned char bos[4096];
  int t = threadIdx.x, lane = t & 63, w = t >> 6;
  int base = blockIdx.x*4096;
  int ed[16]; int bk[16];
  h[t] = 0;
  __syncthreads();
  #pragma unroll
  for (int k = 0; k < 16; ++k){
    int e = base + k*256 + t;
    if (e < E){
      int s = src[e], d = dst[e];
      ed[k] = s | ((d & 255) << 16);
      bk[k] = d >> 8;
      atomicAdd(&h[bk[k]], 1);
    } else bk[k] = -1;
  }
  __syncthreads();
  int v = h[t];
  int incl = v;
  #pragma unroll
  for (int o = 1; o < 64; o <<= 1){
    int x = __shfl_up(incl, o, 64);
    if (lane >= o) incl += x;
  }
  if (lane == 63) wt[w] = incl;
  __syncthreads();
  int woff = 0;
  for (int i = 0; i < w; ++i) woff += wt[i];
  ls[t] = woff + incl - v;
  cur[t] = ls[t];
  if (v > 0) gb[t] = atomicAdd(&bucketCursor[t], v);
  __syncthreads();
  #pragma unroll
  for (int k = 0; k < 16; ++k){
    if (bk[k] >= 0){
      int lp = atomicAdd(&cur[bk[k]], 1);
      staged[lp] = ed[k];
      bos[lp] = (unsigned char)bk[k];
    }
  }
  __syncthreads();
  int nvalid = min(4096, E - base);
  #pragma unroll
  for (int k = 0; k < 16; ++k){
    int i = k*256 + t;
    if (i < nvalid){
      int b = bos[i];
      tmp[gb[b] + (i - ls[b])] = staged[i];
    }
  }
}

// one block per bucket: group by exact dst, emit rowptr/dis/csrc
__global__ __launch_bounds__(256) void k_csr(const int* __restrict__ tmp,
                                             const int* __restrict__ bucketHist,
                                             const int* __restrict__ bucketBase,
                                             int* __restrict__ rowptr,
                                             float* __restrict__ dis,
                                             int* __restrict__ csrc, int N){
  __shared__ int h[256], ls[256], cur[256];
  __shared__ int wt[4];
  __shared__ int stagedSrc[6144];
  int b = blockIdx.x, t = threadIdx.x, lane = t & 63, w = t >> 6;
  int ebase = bucketBase[b];
  int cnt = bucketHist[b];
  int node0 = b << 8;
  h[t] = 0;
  __syncthreads();
  for (int i = t; i < cnt; i += 256)
    atomicAdd(&h[(tmp[ebase + i] >> 16) & 255], 1);
  __syncthreads();
  int v = h[t];
  int incl = v;
  #pragma unroll
  for (int o = 1; o < 64; o <<= 1){
    int x = __shfl_up(incl, o, 64);
    if (lane >= o) incl += x;
  }
  if (lane == 63) wt[w] = incl;
  __syncthreads();
  int woff = 0;
  for (int i = 0; i < w; ++i) woff += wt[i];
  int ex = woff + incl - v;
  ls[t] = ex; cur[t] = ex;
  int d = node0 + t;
  if (d < N){
    rowptr[d+1] = ebase + ex + v;
    dis[d] = rsqrtf((float)v + 1.0f);
  }
  if (b == 0 && t == 0) rowptr[0] = 0;
  __syncthreads();
  for (int i = t; i < cnt; i += 256){
    int e = tmp[ebase + i];
    int lp = atomicAdd(&cur[(e >> 16) & 255], 1);
    stagedSrc[lp] = e & 0xFFFF;
  }
  __syncthreads();
  for (int i = t; i < cnt; i += 256)
    csrc[ebase + i] = stagedSrc[i];
}

// ------------------- GEMM: bf16 MFMA, fused BN-affine+ReLU on A, dis-scale on out ----
// Row-major A (MODE 1: bf16 AGG) and O. MODE 0: A fp32 (= x).
template<int MODE>
__global__ __launch_bounds__(256) void k_gemm(const void* __restrict__ Av,
                                              const ushort* __restrict__ Wf,
                                              const float* __restrict__ sums,
                                              const float* __restrict__ g,
                                              const float* __restrict__ be,
                                              const float* __restrict__ dis,
                                              ushort* __restrict__ O, int n, float invN){
  __shared__ float aL[HD], bL[HD];
  int tid = threadIdx.x;
  if (MODE){
    if (tid < HD){
      float m = sums[tid]*invN;
      float var = fmaxf(sums[HD+tid]*invN - m*m, 0.f);
      float Ac = g[tid]*rsqrtf(var + EPS);
      aL[tid] = Ac; bL[tid] = be[tid] - m*Ac;
    }
    __syncthreads();
  }
  int lane = tid & 63, wave = tid >> 6;
  int quad = lane >> 4, r16 = lane & 15;
  int row = blockIdx.x*64 + wave*16 + r16;
  int rowc = min(row, n-1);
  floatx4 acc[8] = {};
  #pragma unroll
  for (int kb = 0; kb < 4; ++kb){
    int k0 = kb*32 + quad*8;
    short8 af;
    if (MODE){
      const ushort* Arow = (const ushort*)Av + (size_t)rowc*HD;
      short8 raw = *(const short8*)(Arow + k0);
      #pragma unroll
      for (int jj = 0; jj < 8; ++jj){
        float f = bf2f((ushort)raw[jj]);
        f = fmaxf(f*aL[k0+jj] + bL[k0+jj], 0.f);
        af[jj] = (short)f2bf(f);
      }
    } else {
      const float* Arow = (const float*)Av + (size_t)rowc*HD;
      float4 x0 = *(const float4*)(Arow + k0);
      float4 x1 = *(const float4*)(Arow + k0 + 4);
      af[0] = (short)f2bf(x0.x); af[1] = (short)f2bf(x0.y);
      af[2] = (short)f2bf(x0.z); af[3] = (short)f2bf(x0.w);
      af[4] = (short)f2bf(x1.x); af[5] = (short)f2bf(x1.y);
      af[6] = (short)f2bf(x1.z); af[7] = (short)f2bf(x1.w);
    }
    const ushort* wp = Wf + ((size_t)(kb*8)*64 + lane)*8;
    #pragma unroll
    for (int nt = 0; nt < 8; ++nt){
      short8 bf = *(const short8*)(wp + (size_t)nt*64*8);
      acc[nt] = __builtin_amdgcn_mfma_f32_16x16x32_bf16(af, bf, acc[nt], 0, 0, 0);
    }
  }
  int rbase = blockIdx.x*64 + wave*16 + quad*4;
  float ds[4];
  #pragma unroll
  for (int r = 0; r < 4; ++r) ds[r] = dis[min(rbase + r, n-1)];
  #pragma unroll
  for (int nt = 0; nt < 8; ++nt){
    #pragma unroll
    for (int r = 0; r < 4; ++r){
      int rr = rbase + r;
      if (rr < n) O[(size_t)rr*HD + nt*16 + r16] = f2bf(acc[nt][r]*ds[r]);
    }
  }
}

// ------------------- edge aggregation + fused BN-stats partials -------------------
// 16 lanes/node (16B loads), 16 nodes/block, 4 nodes/wave. 8-edge unroll + prefetch.
__global__ __launch_bounds__(256) void k_gather(const ushort* __restrict__ hw,
                                                const int* __restrict__ rowptr,
                                                const int* __restrict__ csrc,
                                                const float* __restrict__ dis,
                                                ushort* __restrict__ agg,
                                                float* __restrict__ scratch,
                                                float* __restrict__ sums, int N){
  __shared__ float2 sm[4][HD];
  if (blockIdx.x == 0) sums[threadIdx.x] = 0.f;   // zero before k_reduce's atomics
  int grp = threadIdx.x >> 4, j = threadIdx.x & 15;
  int wave = threadIdx.x >> 6, lane = threadIdx.x & 63;
  int i = blockIdx.x*16 + grp;
  bool valid = (i < N);
  int ic = valid ? i : N-1;
  uint4 q = ((const uint4*)(hw + (size_t)ic*HD))[j];
  float a[8];
  a[0] = bflo(q.x); a[1] = bfhi(q.x);
  a[2] = bflo(q.y); a[3] = bfhi(q.y);
  a[4] = bflo(q.z); a[5] = bfhi(q.z);
  a[6] = bflo(q.w); a[7] = bfhi(q.w);
  int e = rowptr[ic], e1 = rowptr[ic+1];
  #define ADD8(Q) \
    a[0] += bflo(Q.x); a[1] += bfhi(Q.x); \
    a[2] += bflo(Q.y); a[3] += bfhi(Q.y); \
    a[4] += bflo(Q.z); a[5] += bfhi(Q.z); \
    a[6] += bflo(Q.w); a[7] += bfhi(Q.w);
  while (e < e1 && (e & 3)){
    uint4 qq = ((const uint4*)(hw + (size_t)csrc[e]*HD))[j];
    ADD8(qq);
    e++;
  }
  int4 c0, c1;
  if (e + 8 <= e1){
    c0 = *(const int4*)&csrc[e];
    c1 = *(const int4*)&csrc[e+4];
  }
  while (e + 8 <= e1){
    int en = e + 8;
    int4 n0, n1;
    if (en + 8 <= e1){
      n0 = *(const int4*)&csrc[en];
      n1 = *(const int4*)&csrc[en+4];
    }
    uint4 q0 = ((const uint4*)(hw + (size_t)c0.x*HD))[j];
    uint4 q1 = ((const uint4*)(hw + (size_t)c0.y*HD))[j];
    uint4 q2 = ((const uint4*)(hw + (size_t)c0.z*HD))[j];
    uint4 q3 = ((const uint4*)(hw + (size_t)c0.w*HD))[j];
    uint4 q4 = ((const uint4*)(hw + (size_t)c1.x*HD))[j];
    uint4 q5 = ((const uint4*)(hw + (size_t)c1.y*HD))[j];
    uint4 q6 = ((const uint4*)(hw + (size_t)c1.z*HD))[j];
    uint4 q7 = ((const uint4*)(hw + (size_t)c1.w*HD))[j];
    ADD8(q0); ADD8(q1); ADD8(q2); ADD8(q3);
    ADD8(q4); ADD8(q5); ADD8(q6); ADD8(q7);
    c0 = n0; c1 = n1; e = en;
  }
  if (e + 4 <= e1){
    int4 tt = *(const int4*)&csrc[e];
    uint4 q0 = ((const uint4*)(hw + (size_t)tt.x*HD))[j];
    uint4 q1 = ((const uint4*)(hw + (size_t)tt.y*HD))[j];
    uint4 q2 = ((const uint4*)(hw + (size_t)tt.z*HD))[j];
    uint4 q3 = ((const uint4*)(hw + (size_t)tt.w*HD))[j];
    ADD8(q0); ADD8(q1); ADD8(q2); ADD8(q3);
    e += 4;
  }
  for (; e < e1; ++e){
    uint4 qq = ((const uint4*)(hw + (size_t)csrc[e]*HD))[j];
    ADD8(qq);
  }
  #undef ADD8
  float sc = dis[ic];
  #pragma unroll
  for (int k = 0; k < 8; ++k) a[k] *= sc;
  if (valid){
    uint4 o;
    o.x = (unsigned)f2bf(a[0]) | ((unsigned)f2bf(a[1]) << 16);
    o.y = (unsigned)f2bf(a[2]) | ((unsigned)f2bf(a[3]) << 16);
    o.z = (unsigned)f2bf(a[4]) | ((unsigned)f2bf(a[5]) << 16);
    o.w = (unsigned)f2bf(a[6]) | ((unsigned)f2bf(a[7]) << 16);
    ((uint4*)(agg + (size_t)i*HD))[j] = o;
  }
  float z = valid ? 1.f : 0.f;
  #pragma unroll
  for (int k = 0; k < 8; ++k){
    float s = a[k]*z, qq = a[k]*a[k]*z;
    s  += __shfl_xor(s, 16);  s  += __shfl_xor(s, 32);
    qq += __shfl_xor(qq, 16); qq += __shfl_xor(qq, 32);
    if (lane < 16) sm[wave][lane*8 + k] = make_float2(s, qq);
  }
  __syncthreads();
  int t = threadIdx.x;
  if (t < HD){
    float2 r0 = sm[0][t], r1 = sm[1][t], r2 = sm[2][t], r3 = sm[3][t];
    scratch[(size_t)blockIdx.x*256 + t]      = r0.x + r1.x + r2.x + r3.x;
    scratch[(size_t)blockIdx.x*256 + HD + t] = r0.y + r1.y + r2.y + r3.y;
  }
}

// coalesced second-stage reduction
__global__ __launch_bounds__(256) void k_reduce(const float* __restrict__ scratch,
                                                float* __restrict__ sums, int R){
  int t = threadIdx.x;
  float acc = 0.f;
  for (int r = blockIdx.x; r < R; r += gridDim.x)
    acc += scratch[(size_t)r*256 + t];
  atomicAdd(&sums[t], acc);
}

// ------------------- mean pool (fused layer-3 BN+ReLU, fused counts) -------------------
// block 0 also zeroes sums2 (used by k_fc1's fused stats one dispatch later)
__global__ __launch_bounds__(128) void k_pool(const ushort* __restrict__ h,
                                              const int* __restrict__ batch,
                                              const float* __restrict__ sums,
                                              const float* __restrict__ g,
                                              const float* __restrict__ be,
                                              float* __restrict__ pooled,
                                              float* __restrict__ cntf,
                                              float* __restrict__ sums2, int N, float invN){
  int c = threadIdx.x;
  if (blockIdx.x == 0) sums2[c] = 0.f;   // 128 = 2*FCD floats
  float m = sums[c]*invN;
  float var = fmaxf(sums[HD+c]*invN - m*m, 0.f);
  float a = g[c]*rsqrtf(var + EPS);
  float b = be[c] - m*a;
  int start = blockIdx.x * 32;
  if (start >= N) return;
  int end = min(start + 32, N);
  int cur = batch[start];
  float acc = 0.f; int run = 0;
  for (int i = start; i < end; ++i){
    int bb = batch[i];
    if (bb != cur){
      atomicAdd(&pooled[(size_t)cur*HD + c], acc);
      if (c == 0) atomicAdd(&cntf[cur], (float)run);
      acc = 0.f; run = 0; cur = bb;
    }
    acc += fmaxf(bf2f(h[(size_t)i*HD + c])*a + b, 0.f);
    run++;
  }
  atomicAdd(&pooled[(size_t)cur*HD + c], acc);
  if (c == 0) atomicAdd(&cntf[cur], (float)run);
}

// ------------------- FC head (fc1 with fused BN stats) -------------------

__global__ __launch_bounds__(64) void k_fc1(const float* __restrict__ pooled,
                                            const float* __restrict__ cntf,
                                            const float* __restrict__ W,
                                            const float* __restrict__ b,
                                            float* __restrict__ z,
                                            float* __restrict__ sums2, int G){
  int g = blockIdx.x, j = threadIdx.x;
  float inv = 1.0f / fmaxf(cntf[g], 1.0f);
  float acc = 0.f;
  for (int k = 0; k < HD; ++k)
    acc += pooled[(size_t)g*HD + k] * W[k*FCD + j];
  float zv = acc * inv + b[j];
  z[(size_t)g*FCD + j] = zv;
  atomicAdd(&sums2[j], zv);
  atomicAdd(&sums2[FCD + j], zv*zv);
}

__global__ __launch_bounds__(64) void k_final(const float* __restrict__ z,
                                              const float* __restrict__ sums2,
                                              const float* __restrict__ g,
                                              const float* __restrict__ be,
                                              const float* __restrict__ w2,
                                              const float* __restrict__ b2,
                                              float* __restrict__ out, int G, float invG){
  int gg = blockIdx.x, c = threadIdx.x;
  float m = sums2[c]*invG;
  float var = fmaxf(sums2[FCD+c]*invG - m*m, 0.f);
  float A = g[c]*rsqrtf(var + EPS);
  float B = be[c] - m*A;
  float v = fmaxf(z[(size_t)gg*FCD + c]*A + B, 0.f) * w2[c];
  #pragma unroll
  for (int o = 32; o > 0; o >>= 1) v += __shfl_down(v, o, 64);
  if (c == 0) out[gg] = v + b2[0];
}

// ------------------- launch -------------------

extern "C" void kernel_launch(void* const* d_in, const int* in_sizes, int n_in,
                              void* d_out, int out_size, void* d_ws, size_t ws_size,
                              hipStream_t stream){
  const float* x    = (const float*)d_in[0];
  const int*   ei   = (const int*)d_in[1];
  const int*   batch= (const int*)d_in[2];
  const float* W1 = (const float*)d_in[3];
  const float* g1 = (const float*)d_in[5];
  const float* be1= (const float*)d_in[6];
  const float* W2 = (const float*)d_in[7];
  const float* g2 = (const float*)d_in[9];
  const float* be2= (const float*)d_in[10];
  const float* W3 = (const float*)d_in[11];
  const float* g3 = (const float*)d_in[13];
  const float* be3= (const float*)d_in[14];
  const float* fcW1 = (const float*)d_in[15];
  const float* fcb1 = (const float*)d_in[16];
  const float* fcg1 = (const float*)d_in[17];
  const float* fcbe1= (const float*)d_in[18];
  const float* fcW2 = (const float*)d_in[19];
  const float* fcb2 = (const float*)d_in[20];
  float* out = (float*)d_out;

  const int N = in_sizes[0] / HD;      // 50000 (fits 16-bit pack: N < 65536)
  const int E = in_sizes[1] / 2;       // 800000
  const int G = out_size;              // 500

  const int* esrc = ei;
  const int* edst = ei + E;

  char* p = (char*)d_ws;
  auto alloc = [&](size_t bytes)->void*{
    void* r = (void*)p; p += (bytes + 255) & ~(size_t)255; return r;
  };
  int gatherBlocks = (N + 15)/16;
  int nEB = (E + 4095)/4096;           // 196 edge blocks
  int NB  = (N + 255)/256;             // 196 node buckets (<=256 required)
  int poolSz = G*HD + G;
  int PZ = (poolSz + 1023)/1024;
  int*    bucketHist  = (int*) alloc(256*4);
  int*    bucketBase  = (int*) alloc(256*4);
  int*    bucketCursor= (int*) alloc(256*4);
  int*    tmp    = (int*)   alloc((size_t)E*4);
  int*    rowptr = (int*)   alloc((size_t)(N+1)*4);
  int*    csrc   = (int*)   alloc((size_t)E*4);
  float*  dis    = (float*) alloc((size_t)N*4);
  ushort* HWb    = (ushort*)alloc((size_t)N*HD*2);
  ushort* AGG    = (ushort*)alloc((size_t)N*HD*2);
  ushort* Wf     = (ushort*)alloc((size_t)3*HD*HD*2);
  float*  sums   = (float*) alloc(2*HD*4);
  float*  scratch= (float*) alloc((size_t)gatherBlocks*256*4);
  float*  pooled = (float*) alloc(((size_t)G*HD + G)*4);
  float*  cntf   = pooled + (size_t)G*HD;
  float*  zbuf   = (float*) alloc((size_t)G*FCD*4);
  float*  sums2  = (float*) alloc(2*FCD*4);

  float invN = 1.0f/(float)N, invG = 1.0f/(float)G;

  // CSR build (bucket sort) + fused W-pack + pooled zero
  hipMemsetAsync(bucketHist, 0, 256*4, stream);
  k_pre   <<<nEB + 192 + PZ, 256, 0, stream>>>(edst, bucketHist, E, nEB,
                                               W1, W2, W3, Wf, pooled, poolSz);
  k_bscan <<<1, 256, 0, stream>>>(bucketHist, bucketBase, bucketCursor);
  k_bucket<<<nEB, 256, 0, stream>>>(esrc, edst, bucketCursor, tmp, E);
  k_csr   <<<NB, 256, 0, stream>>>(tmp, bucketHist, bucketBase, rowptr, dis, csrc, N);

  int gemmBlocks = (N + 63)/64;

  // layer 1
  k_gemm<0> <<<gemmBlocks, 256, 0, stream>>>(x,   Wf,         nullptr, nullptr, nullptr, dis, HWb, N, invN);
  k_gather  <<<gatherBlocks, 256, 0, stream>>>(HWb, rowptr, csrc, dis, AGG, scratch, sums, N);
  k_reduce  <<<64, 256, 0, stream>>>(scratch, sums, gatherBlocks);
  // layer 2 (BN1+ReLU fused into A-load)
  k_gemm<1> <<<gemmBlocks, 256, 0, stream>>>(AGG, Wf + 16384, sums, g1, be1, dis, HWb, N, invN);
  k_gather  <<<gatherBlocks, 256, 0, stream>>>(HWb, rowptr, csrc, dis, AGG, scratch, sums, N);
  k_reduce  <<<64, 256, 0, stream>>>(scratch, sums, gatherBlocks);
  // layer 3 (BN2+ReLU fused into A-load)
  k_gemm<1> <<<gemmBlocks, 256, 0, stream>>>(AGG, Wf + 32768, sums, g2, be2, dis, HWb, N, invN);
  k_gather  <<<gatherBlocks, 256, 0, stream>>>(HWb, rowptr, csrc, dis, AGG, scratch, sums, N);
  k_reduce  <<<64, 256, 0, stream>>>(scratch, sums, gatherBlocks);

  // pool (BN3+ReLU fused, zeroes sums2) + head
  k_pool  <<<(N+31)/32, 128, 0, stream>>>(AGG, batch, sums, g3, be3, pooled, cntf, sums2, N, invN);
  k_fc1   <<<G, FCD, 0, stream>>>(pooled, cntf, fcW1, fcb1, zbuf, sums2, G);
  k_final <<<G, FCD, 0, stream>>>(zbuf, sums2, fcg1, fcbe1, fcW2, fcb2, out, G, invG);
}

// Round 9
// 364.727 us; speedup vs baseline: 1.0338x; 1.0044x over previous
//
#include <hip/hip_runtime.h>

#define EPS 1e-5f
constexpr int HD = 128;   // node feature / hidden dim
constexpr int FCD = 64;   // fc hidden dim

typedef __attribute__((ext_vector_type(8))) short short8;
typedef __attribute__((ext_vector_type(4))) float floatx4;

// ---------- bf16 helpers ----------
__device__ inline ushort f2bf(float f){
  union{float f; unsigned u;} v; v.f = f;
  unsigned r = v.u + 0x7FFFu + ((v.u >> 16) & 1u);
  return (ushort)(r >> 16);
}
__device__ inline float bflo(unsigned u){ union{unsigned i; float f;} v; v.i = u << 16;        return v.f; }
__device__ inline float bfhi(unsigned u){ union{unsigned i; float f;} v; v.i = u & 0xFFFF0000u; return v.f; }
__device__ inline float bf2f(ushort u){ union{unsigned i; float f;} v; v.i = ((unsigned)u) << 16; return v.f; }

// ================= preprocessing =================
// k_pre: fused [bucket histogram | W fragment pack | pooled+cntf zeroing]
__global__ __launch_bounds__(256) void k_pre(const int* __restrict__ dst,
                                             int* __restrict__ bucketHist, int E, int nEB,
                                             const float* __restrict__ W1,
                                             const float* __restrict__ W2,
                                             const float* __restrict__ W3,
                                             ushort* __restrict__ Wf,
                                             float* __restrict__ pooled, int poolSz){
  __shared__ int h[256];
  int bid = blockIdx.x, t = threadIdx.x;
  if (bid < nEB){
    h[t] = 0;
    __syncthreads();
    int base = bid*4096;
    #pragma unroll
    for (int k = 0; k < 16; ++k){
      int e = base + k*256 + t;
      if (e < E) atomicAdd(&h[dst[e] >> 8], 1);
    }
    __syncthreads();
    if (h[t]) atomicAdd(&bucketHist[t], h[t]);
  } else if (bid < nEB + 192){
    int j = bid - nEB;
    int l = j >> 6;
    int idx = (j & 63)*256 + t;             // 0..16383
    const float* W = (l == 0) ? W1 : (l == 1) ? W2 : W3;
    float w = W[idx];
    int k = idx >> 7, n = idx & 127;
    int kb = k >> 5, q4 = (k >> 3) & 3, jj = k & 7;
    int nt = n >> 4, col = n & 15;
    Wf[(size_t)l*16384 + (((size_t)(kb*8 + nt)*64 + q4*16 + col)*8 + jj)] = f2bf(w);
  } else {
    int j = bid - nEB - 192;
    int base = (j*256 + t)*4;
    #pragma unroll
    for (int k = 0; k < 4; ++k){
      int o = base + k;
      if (o < poolSz) pooled[o] = 0.f;
    }
  }
}

// 1 block: exclusive scan of 256 bucket counts -> base & cursor
__global__ __launch_bounds__(256) void k_bscan(const int* __restrict__ bucketHist,
                                               int* __restrict__ bucketBase,
                                               int* __restrict__ bucketCursor){
  __shared__ int wt[4];
  int t = threadIdx.x, lane = t & 63, w = t >> 6;
  int v = bucketHist[t];
  int incl = v;
  #pragma unroll
  for (int o = 1; o < 64; o <<= 1){
    int x = __shfl_up(incl, o, 64);
    if (lane >= o) incl += x;
  }
  if (lane == 63) wt[w] = incl;
  __syncthreads();
  int woff = 0;
  for (int i = 0; i < w; ++i) woff += wt[i];
  int ex = woff + incl - v;
  bucketBase[t] = ex;
  bucketCursor[t] = ex;
}

// LDS-staged bucket scatter; edge packed into one int: src | (dst&255)<<16
__global__ __launch_bounds__(256) void k_bucket(const int* __restrict__ src,
                                                const int* __restrict__ dst,
                                                int* __restrict__ bucketCursor,
                                                int* __restrict__ tmp, int E){
  __shared__ int h[256], ls[256], cur[256], gb[256];
  __shared__ int wt[4];
  __shared__ int staged[4096];
  __shared__ unsigned char bos[4096];
  int t = threadIdx.x, lane = t & 63, w = t >> 6;
  int base = blockIdx.x*4096;
  int ed[16]; int bk[16];
  h[t] = 0;
  __syncthreads();
  #pragma unroll
  for (int k = 0; k < 16; ++k){
    int e = base + k*256 + t;
    if (e < E){
      int s = src[e], d = dst[e];
      ed[k] = s | ((d & 255) << 16);
      bk[k] = d >> 8;
      atomicAdd(&h[bk[k]], 1);
    } else bk[k] = -1;
  }
  __syncthreads();
  int v = h[t];
  int incl = v;
  #pragma unroll
  for (int o = 1; o < 64; o <<= 1){
    int x = __shfl_up(incl, o, 64);
    if (lane >= o) incl += x;
  }
  if (lane == 63) wt[w] = incl;
  __syncthreads();
  int woff = 0;
  for (int i = 0; i < w; ++i) woff += wt[i];
  ls[t] = woff + incl - v;
  cur[t] = ls[t];
  if (v > 0) gb[t] = atomicAdd(&bucketCursor[t], v);
  __syncthreads();
  #pragma unroll
  for (int k = 0; k < 16; ++k){
    if (bk[k] >= 0){
      int lp = atomicAdd(&cur[bk[k]], 1);
      staged[lp] = ed[k];
      bos[lp] = (unsigned char)bk[k];
    }
  }
  __syncthreads();
  int nvalid = min(4096, E - base);
  #pragma unroll
  for (int k = 0; k < 16; ++k){
    int i = k*256 + t;
    if (i < nvalid){
      int b = bos[i];
      tmp[gb[b] + (i - ls[b])] = staged[i];
    }
  }
}

// one block per bucket: group by exact dst, emit rowptr/dis/csrc
__global__ __launch_bounds__(256) void k_csr(const int* __restrict__ tmp,
                                             const int* __restrict__ bucketHist,
                                             const int* __restrict__ bucketBase,
                                             int* __restrict__ rowptr,
                                             float* __restrict__ dis,
                                             int* __restrict__ csrc, int N){
  __shared__ int h[256], ls[256], cur[256];
  __shared__ int wt[4];
  __shared__ int stagedSrc[6144];
  int b = blockIdx.x, t = threadIdx.x, lane = t & 63, w = t >> 6;
  int ebase = bucketBase[b];
  int cnt = bucketHist[b];
  int node0 = b << 8;
  h[t] = 0;
  __syncthreads();
  for (int i = t; i < cnt; i += 256)
    atomicAdd(&h[(tmp[ebase + i] >> 16) & 255], 1);
  __syncthreads();
  int v = h[t];
  int incl = v;
  #pragma unroll
  for (int o = 1; o < 64; o <<= 1){
    int x = __shfl_up(incl, o, 64);
    if (lane >= o) incl += x;
  }
  if (lane == 63) wt[w] = incl;
  __syncthreads();
  int woff = 0;
  for (int i = 0; i < w; ++i) woff += wt[i];
  int ex = woff + incl - v;
  ls[t] = ex; cur[t] = ex;
  int d = node0 + t;
  if (d < N){
    rowptr[d+1] = ebase + ex + v;
    dis[d] = rsqrtf((float)v + 1.0f);
  }
  if (b == 0 && t == 0) rowptr[0] = 0;
  __syncthreads();
  for (int i = t; i < cnt; i += 256){
    int e = tmp[ebase + i];
    int lp = atomicAdd(&cur[(e >> 16) & 255], 1);
    stagedSrc[lp] = e & 0xFFFF;
  }
  __syncthreads();
  for (int i = t; i < cnt; i += 256)
    csrc[ebase + i] = stagedSrc[i];
}

// ------------------- GEMM: bf16 MFMA, fused BN-affine+ReLU on A, dis-scale on out ----
template<int MODE>
__global__ __launch_bounds__(256) void k_gemm(const void* __restrict__ Av,
                                              const ushort* __restrict__ Wf,
                                              const float* __restrict__ sums,
                                              const float* __restrict__ g,
                                              const float* __restrict__ be,
                                              const float* __restrict__ dis,
                                              ushort* __restrict__ O, int n, float invN){
  __shared__ float aL[HD], bL[HD];
  int tid = threadIdx.x;
  if (MODE){
    if (tid < HD){
      float m = sums[tid]*invN;
      float var = fmaxf(sums[HD+tid]*invN - m*m, 0.f);
      float Ac = g[tid]*rsqrtf(var + EPS);
      aL[tid] = Ac; bL[tid] = be[tid] - m*Ac;
    }
    __syncthreads();
  }
  int lane = tid & 63, wave = tid >> 6;
  int quad = lane >> 4, r16 = lane & 15;
  int row = blockIdx.x*64 + wave*16 + r16;
  int rowc = min(row, n-1);
  floatx4 acc[8] = {};
  #pragma unroll
  for (int kb = 0; kb < 4; ++kb){
    int k0 = kb*32 + quad*8;
    short8 af;
    if (MODE){
      const ushort* Arow = (const ushort*)Av + (size_t)rowc*HD;
      short8 raw = *(const short8*)(Arow + k0);
      #pragma unroll
      for (int jj = 0; jj < 8; ++jj){
        float f = bf2f((ushort)raw[jj]);
        f = fmaxf(f*aL[k0+jj] + bL[k0+jj], 0.f);
        af[jj] = (short)f2bf(f);
      }
    } else {
      const float* Arow = (const float*)Av + (size_t)rowc*HD;
      float4 x0 = *(const float4*)(Arow + k0);
      float4 x1 = *(const float4*)(Arow + k0 + 4);
      af[0] = (short)f2bf(x0.x); af[1] = (short)f2bf(x0.y);
      af[2] = (short)f2bf(x0.z); af[3] = (short)f2bf(x0.w);
      af[4] = (short)f2bf(x1.x); af[5] = (short)f2bf(x1.y);
      af[6] = (short)f2bf(x1.z); af[7] = (short)f2bf(x1.w);
    }
    const ushort* wp = Wf + ((size_t)(kb*8)*64 + lane)*8;
    #pragma unroll
    for (int nt = 0; nt < 8; ++nt){
      short8 bf = *(const short8*)(wp + (size_t)nt*64*8);
      acc[nt] = __builtin_amdgcn_mfma_f32_16x16x32_bf16(af, bf, acc[nt], 0, 0, 0);
    }
  }
  int rbase = blockIdx.x*64 + wave*16 + quad*4;
  float ds[4];
  #pragma unroll
  for (int r = 0; r < 4; ++r) ds[r] = dis[min(rbase + r, n-1)];
  #pragma unroll
  for (int nt = 0; nt < 8; ++nt){
    #pragma unroll
    for (int r = 0; r < 4; ++r){
      int rr = rbase + r;
      if (rr < n) O[(size_t)rr*HD + nt*16 + r16] = f2bf(acc[nt][r]*ds[r]);
    }
  }
}

// ------------------- edge aggregation + fused BN-stats partials -------------------
// Wave = 4 edge-slots x 16 channel-chunks; processes its 4 nodes SEQUENTIALLY.
// Loop bounds wave-uniform -> zero inter-node divergence; tail quad exec-masked
// -> zero bandwidth waste. Slot reduction via shfl_xor(16/32).
__global__ __launch_bounds__(256) void k_gather(const ushort* __restrict__ hw,
                                                const int* __restrict__ rowptr,
                                                const int* __restrict__ csrc,
                                                const float* __restrict__ dis,
                                                ushort* __restrict__ agg,
                                                float* __restrict__ scratch,
                                                float* __restrict__ sums, int N){
  __shared__ float2 sm[4][HD];
  if (blockIdx.x == 0) sums[threadIdx.x] = 0.f;   // zero before k_reduce's atomics
  int wave = threadIdx.x >> 6, lane = threadIdx.x & 63;
  int slot = lane >> 4, j = lane & 15;
  float ss[8] = {0,0,0,0,0,0,0,0}, sq[8] = {0,0,0,0,0,0,0,0};
  int ibase = blockIdx.x*16 + wave*4;
  #define ADD8(Q) \
    a[0] += bflo(Q.x); a[1] += bfhi(Q.x); \
    a[2] += bflo(Q.y); a[3] += bfhi(Q.y); \
    a[4] += bflo(Q.z); a[5] += bfhi(Q.z); \
    a[6] += bflo(Q.w); a[7] += bfhi(Q.w);
  for (int nn = 0; nn < 4; ++nn){
    int i = ibase + nn;
    bool valid = (i < N);
    int ic = valid ? i : N-1;
    float a[8] = {0,0,0,0,0,0,0,0};
    if (slot == 0){                        // self term loaded by slot 0
      uint4 q = ((const uint4*)(hw + (size_t)ic*HD))[j];
      ADD8(q);
    }
    int e = rowptr[ic], e1 = rowptr[ic+1];
    // main: 8 edges/iteration (2 full quads), unmasked
    for (; e + 8 <= e1; e += 8){
      int s0 = csrc[e + slot];
      int s1 = csrc[e + 4 + slot];
      uint4 q0 = ((const uint4*)(hw + (size_t)s0*HD))[j];
      uint4 q1 = ((const uint4*)(hw + (size_t)s1*HD))[j];
      ADD8(q0); ADD8(q1);
    }
    // tail: up to 2 exec-masked quad iterations (exact loads, no waste)
    for (; e < e1; e += 4){
      int ii = e + slot;
      if (ii < e1){
        uint4 q = ((const uint4*)(hw + (size_t)csrc[ii]*HD))[j];
        ADD8(q);
      }
    }
    // reduce across the 4 slots (j preserved under xor 16/32)
    #pragma unroll
    for (int k = 0; k < 8; ++k){
      a[k] += __shfl_xor(a[k], 16);
      a[k] += __shfl_xor(a[k], 32);
    }
    float sc = dis[ic] * (valid ? 1.f : 0.f);
    #pragma unroll
    for (int k = 0; k < 8; ++k) a[k] *= sc;
    if (valid && slot == 0){
      uint4 o;
      o.x = (unsigned)f2bf(a[0]) | ((unsigned)f2bf(a[1]) << 16);
      o.y = (unsigned)f2bf(a[2]) | ((unsigned)f2bf(a[3]) << 16);
      o.z = (unsigned)f2bf(a[4]) | ((unsigned)f2bf(a[5]) << 16);
      o.w = (unsigned)f2bf(a[6]) | ((unsigned)f2bf(a[7]) << 16);
      ((uint4*)(agg + (size_t)i*HD))[j] = o;
    }
    #pragma unroll
    for (int k = 0; k < 8; ++k){ ss[k] += a[k]; sq[k] += a[k]*a[k]; }
  }
  #undef ADD8
  if (lane < 16){
    #pragma unroll
    for (int k = 0; k < 8; ++k) sm[wave][j*8 + k] = make_float2(ss[k], sq[k]);
  }
  __syncthreads();
  int t = threadIdx.x;
  if (t < HD){
    float2 r0 = sm[0][t], r1 = sm[1][t], r2 = sm[2][t], r3 = sm[3][t];
    scratch[(size_t)blockIdx.x*256 + t]      = r0.x + r1.x + r2.x + r3.x;
    scratch[(size_t)blockIdx.x*256 + HD + t] = r0.y + r1.y + r2.y + r3.y;
  }
}

// coalesced second-stage reduction
__global__ __launch_bounds__(256) void k_reduce(const float* __restrict__ scratch,
                                                float* __restrict__ sums, int R){
  int t = threadIdx.x;
  float acc = 0.f;
  for (int r = blockIdx.x; r < R; r += gridDim.x)
    acc += scratch[(size_t)r*256 + t];
  atomicAdd(&sums[t], acc);
}

// ------------------- mean pool (fused layer-3 BN+ReLU, fused counts) -------------------
__global__ __launch_bounds__(128) void k_pool(const ushort* __restrict__ h,
                                              const int* __restrict__ batch,
                                              const float* __restrict__ sums,
                                              const float* __restrict__ g,
                                              const float* __restrict__ be,
                                              float* __restrict__ pooled,
                                              float* __restrict__ cntf,
                                              float* __restrict__ sums2, int N, float invN){
  int c = threadIdx.x;
  if (blockIdx.x == 0) sums2[c] = 0.f;   // 128 = 2*FCD floats
  float m = sums[c]*invN;
  float var = fmaxf(sums[HD+c]*invN - m*m, 0.f);
  float a = g[c]*rsqrtf(var + EPS);
  float b = be[c] - m*a;
  int start = blockIdx.x * 32;
  if (start >= N) return;
  int end = min(start + 32, N);
  int cur = batch[start];
  float acc = 0.f; int run = 0;
  for (int i = start; i < end; ++i){
    int bb = batch[i];
    if (bb != cur){
      atomicAdd(&pooled[(size_t)cur*HD + c], acc);
      if (c == 0) atomicAdd(&cntf[cur], (float)run);
      acc = 0.f; run = 0; cur = bb;
    }
    acc += fmaxf(bf2f(h[(size_t)i*HD + c])*a + b, 0.f);
    run++;
  }
  atomicAdd(&pooled[(size_t)cur*HD + c], acc);
  if (c == 0) atomicAdd(&cntf[cur], (float)run);
}

// ------------------- FC head (fc1 with fused BN stats) -------------------

__global__ __launch_bounds__(64) void k_fc1(const float* __restrict__ pooled,
                                            const float* __restrict__ cntf,
                                            const float* __restrict__ W,
                                            const float* __restrict__ b,
                                            float* __restrict__ z,
                                            float* __restrict__ sums2, int G){
  int g = blockIdx.x, j = threadIdx.x;
  float inv = 1.0f / fmaxf(cntf[g], 1.0f);
  float acc = 0.f;
  for (int k = 0; k < HD; ++k)
    acc += pooled[(size_t)g*HD + k] * W[k*FCD + j];
  float zv = acc * inv + b[j];
  z[(size_t)g*FCD + j] = zv;
  atomicAdd(&sums2[j], zv);
  atomicAdd(&sums2[FCD + j], zv*zv);
}

__global__ __launch_bounds__(64) void k_final(const float* __restrict__ z,
                                              const float* __restrict__ sums2,
                                              const float* __restrict__ g,
                                              const float* __restrict__ be,
                                              const float* __restrict__ w2,
                                              const float* __restrict__ b2,
                                              float* __restrict__ out, int G, float invG){
  int gg = blockIdx.x, c = threadIdx.x;
  float m = sums2[c]*invG;
  float var = fmaxf(sums2[FCD+c]*invG - m*m, 0.f);
  float A = g[c]*rsqrtf(var + EPS);
  float B = be[c] - m*A;
  float v = fmaxf(z[(size_t)gg*FCD + c]*A + B, 0.f) * w2[c];
  #pragma unroll
  for (int o = 32; o > 0; o >>= 1) v += __shfl_down(v, o, 64);
  if (c == 0) out[gg] = v + b2[0];
}

// ------------------- launch -------------------

extern "C" void kernel_launch(void* const* d_in, const int* in_sizes, int n_in,
                              void* d_out, int out_size, void* d_ws, size_t ws_size,
                              hipStream_t stream){
  const float* x    = (const float*)d_in[0];
  const int*   ei   = (const int*)d_in[1];
  const int*   batch= (const int*)d_in[2];
  const float* W1 = (const float*)d_in[3];
  const float* g1 = (const float*)d_in[5];
  const float* be1= (const float*)d_in[6];
  const float* W2 = (const float*)d_in[7];
  const float* g2 = (const float*)d_in[9];
  const float* be2= (const float*)d_in[10];
  const float* W3 = (const float*)d_in[11];
  const float* g3 = (const float*)d_in[13];
  const float* be3= (const float*)d_in[14];
  const float* fcW1 = (const float*)d_in[15];
  const float* fcb1 = (const float*)d_in[16];
  const float* fcg1 = (const float*)d_in[17];
  const float* fcbe1= (const float*)d_in[18];
  const float* fcW2 = (const float*)d_in[19];
  const float* fcb2 = (const float*)d_in[20];
  float* out = (float*)d_out;

  const int N = in_sizes[0] / HD;      // 50000 (fits 16-bit pack: N < 65536)
  const int E = in_sizes[1] / 2;       // 800000
  const int G = out_size;              // 500

  const int* esrc = ei;
  const int* edst = ei + E;

  char* p = (char*)d_ws;
  auto alloc = [&](size_t bytes)->void*{
    void* r = (void*)p; p += (bytes + 255) & ~(size_t)255; return r;
  };
  int gatherBlocks = (N + 15)/16;
  int nEB = (E + 4095)/4096;           // 196 edge blocks
  int NB  = (N + 255)/256;             // 196 node buckets (<=256 required)
  int poolSz = G*HD + G;
  int PZ = (poolSz + 1023)/1024;
  int*    bucketHist  = (int*) alloc(256*4);
  int*    bucketBase  = (int*) alloc(256*4);
  int*    bucketCursor= (int*) alloc(256*4);
  int*    tmp    = (int*)   alloc((size_t)E*4);
  int*    rowptr = (int*)   alloc((size_t)(N+1)*4);
  int*    csrc   = (int*)   alloc((size_t)E*4);
  float*  dis    = (float*) alloc((size_t)N*4);
  ushort* HWb    = (ushort*)alloc((size_t)N*HD*2);
  ushort* AGG    = (ushort*)alloc((size_t)N*HD*2);
  ushort* Wf     = (ushort*)alloc((size_t)3*HD*HD*2);
  float*  sums   = (float*) alloc(2*HD*4);
  float*  scratch= (float*) alloc((size_t)gatherBlocks*256*4);
  float*  pooled = (float*) alloc(((size_t)G*HD + G)*4);
  float*  cntf   = pooled + (size_t)G*HD;
  float*  zbuf   = (float*) alloc((size_t)G*FCD*4);
  float*  sums2  = (float*) alloc(2*FCD*4);

  float invN = 1.0f/(float)N, invG = 1.0f/(float)G;

  // CSR build (bucket sort) + fused W-pack + pooled zero
  hipMemsetAsync(bucketHist, 0, 256*4, stream);
  k_pre   <<<nEB + 192 + PZ, 256, 0, stream>>>(edst, bucketHist, E, nEB,
                                               W1, W2, W3, Wf, pooled, poolSz);
  k_bscan <<<1, 256, 0, stream>>>(bucketHist, bucketBase, bucketCursor);
  k_bucket<<<nEB, 256, 0, stream>>>(esrc, edst, bucketCursor, tmp, E);
  k_csr   <<<NB, 256, 0, stream>>>(tmp, bucketHist, bucketBase, rowptr, dis, csrc, N);

  int gemmBlocks = (N + 63)/64;

  // layer 1
  k_gemm<0> <<<gemmBlocks, 256, 0, stream>>>(x,   Wf,         nullptr, nullptr, nullptr, dis, HWb, N, invN);
  k_gather  <<<gatherBlocks, 256, 0, stream>>>(HWb, rowptr, csrc, dis, AGG, scratch, sums, N);
  k_reduce  <<<64, 256, 0, stream>>>(scratch, sums, gatherBlocks);
  // layer 2 (BN1+ReLU fused into A-load)
  k_gemm<1> <<<gemmBlocks, 256, 0, stream>>>(AGG, Wf + 16384, sums, g1, be1, dis, HWb, N, invN);
  k_gather  <<<gatherBlocks, 256, 0, stream>>>(HWb, rowptr, csrc, dis, AGG, scratch, sums, N);
  k_reduce  <<<64, 256, 0, stream>>>(scratch, sums, gatherBlocks);
  // layer 3 (BN2+ReLU fused into A-load)
  k_gemm<1> <<<gemmBlocks, 256, 0, stream>>>(AGG, Wf + 32768, sums, g2, be2, dis, HWb, N, invN);
  k_gather  <<<gatherBlocks, 256, 0, stream>>>(HWb, rowptr, csrc, dis, AGG, scratch, sums, N);
  k_reduce  <<<64, 256, 0, stream>>>(scratch, sums, gatherBlocks);

  // pool (BN3+ReLU fused, zeroes sums2) + head
  k_pool  <<<(N+31)/32, 128, 0, stream>>>(AGG, batch, sums, g3, be3, pooled, cntf, sums2, N, invN);
  k_fc1   <<<G, FCD, 0, stream>>>(pooled, cntf, fcW1, fcb1, zbuf, sums2, G);
  k_final <<<G, FCD, 0, stream>>>(zbuf, sums2, fcg1, fcbe1, fcW2, fcb2, out, G, invG);
}